// Round 5
// baseline (454.499 us; speedup 1.0000x reference)
//
#include <hip/hip_runtime.h>
#include <math.h>

// feat_arm/feat_up: [16,144,64,64] f32
// off_w: [144,288,3,3], off_b: [144]
// dcn_w: [256,144,3,3], dcn_b: [256]
// out: [16,256,64,64] f32 (silu)
constexpr int BN = 16;
constexpr int C_IN = 144, C_CAT = 288, C_OFF = 144, C_OUT = 256;
constexpr int OFFG = 8, CG = 18;

constexpr int OFF_ELEMS = BN * C_OFF * 64 * 64;   // fp32 offsets in ws
constexpr int WOFF_PACK = 9 * 9 * 9 * 512;        // 373248 bf16 (cb,tap,mtile,lane,i)
constexpr int WDCN_PACK = 8 * 6 * 16 * 512;       // 393216 bf16 (t=g*6+ks, mtile, lane, i)

typedef __attribute__((ext_vector_type(8))) short bf16x8;
typedef __attribute__((ext_vector_type(4))) float f32x4;

__device__ __forceinline__ unsigned short f2bf(float f) {
  unsigned u = __builtin_bit_cast(unsigned, f);
  return (unsigned short)((u + 0x7FFFu + ((u >> 16) & 1u)) >> 16);  // RNE, finite inputs
}

__device__ __forceinline__ unsigned packh2(float a, float b) {
  unsigned short ha = __builtin_bit_cast(unsigned short, (_Float16)a);
  unsigned short hb = __builtin_bit_cast(unsigned short, (_Float16)b);
  return (unsigned)ha | ((unsigned)hb << 16);
}
__device__ __forceinline__ float h2f_lo(unsigned u) {
  return (float)__builtin_bit_cast(_Float16, (unsigned short)(u & 0xFFFFu));
}
__device__ __forceinline__ float h2f_hi(unsigned u) {
  return (float)__builtin_bit_cast(_Float16, (unsigned short)(u >> 16));
}

// ---------------------------------------------------------------------------
// Kernel 1: pack both weight tensors into MFMA A-fragment order (bf16).
// A-frag slot (lane, i) of a 16x32 tile: m = lane&15, k = (lane>>4)*8 + i.
// (identical to round-3 proven version)
// ---------------------------------------------------------------------------
__global__ __launch_bounds__(256) void pack_w(
    const float* __restrict__ off_w, const float* __restrict__ dcn_w,
    unsigned short* __restrict__ wo, unsigned short* __restrict__ wd) {
  int idx = blockIdx.x * 256 + threadIdx.x;
  if (idx < WOFF_PACK) {
    int i = idx & 7, lane = (idx >> 3) & 63, t = idx >> 9;
    int mt = t % 9; t /= 9;
    int tap = t % 9, cb = t / 9;
    int co = mt * 16 + (lane & 15);
    int ci = cb * 32 + ((lane >> 4) << 3) + i;
    wo[idx] = f2bf(off_w[(co * C_CAT + ci) * 9 + tap]);
  }
  if (idx < WDCN_PACK) {
    int i = idx & 7, lane = (idx >> 3) & 63, t = idx >> 9;
    int mt = t & 15; t >>= 4;
    int ks = t % 6, g = t / 6;
    int co = mt * 16 + (lane & 15);
    int r = ks * 32 + ((lane >> 4) << 3) + i;
    float v = 0.f;
    if (r < 162) {
      int ci = r / 9, tap = r - ci * 9;
      v = dcn_w[(co * C_IN + g * CG + ci) * 9 + tap];
    }
    wd[idx] = f2bf(v);
  }
}

// ---------------------------------------------------------------------------
// Kernel 2: offset conv via MFMA (9 shifted GEMMs). Identical to round 3.
// ---------------------------------------------------------------------------
__global__ __launch_bounds__(256) void offs_conv_mfma(
    const float* __restrict__ fa, const float* __restrict__ fu,
    const unsigned short* __restrict__ wt, const float* __restrict__ bias,
    float* __restrict__ out) {
  const int b = blockIdx.x >> 5;
  const int y0 = (blockIdx.x & 31) << 1;
  const int tid = threadIdx.x;
  const int wave = tid >> 6, lane = tid & 63;
  const int kg = lane >> 4, ln = lane & 15;

  __shared__ __align__(16) unsigned short xs[4 * 66 * 32];

  f32x4 acc[9][2];
#pragma unroll
  for (int m = 0; m < 9; ++m)
#pragma unroll
    for (int n = 0; n < 2; ++n) acc[m][n] = {0.f, 0.f, 0.f, 0.f};

  for (int cb = 0; cb < 9; ++cb) {
    __syncthreads();
    for (int idx = tid; idx < 2112; idx += 256) {
      int q = idx / 264;
      int rem = idx - q * 264;
      int row = rem / 66;
      int cc = rem - row * 66;
      int y = y0 - 1 + row, x = cc - 1;
      ushort4 wv = make_ushort4(0, 0, 0, 0);
      if (y >= 0 && y < 64 && x >= 0 && x < 64) {
        int cib = cb * 32 + (q << 2);
        const float* p = (cib < C_IN)
                             ? fa + (((size_t)(b * C_IN + cib)) << 12)
                             : fu + (((size_t)(b * C_IN + cib - C_IN)) << 12);
        int o = (y << 6) + x;
        wv.x = f2bf(p[o]);
        wv.y = f2bf(p[o + 4096]);
        wv.z = f2bf(p[o + 8192]);
        wv.w = f2bf(p[o + 12288]);
      }
      int e = ((row * 66 + cc) << 5) + (((q >> 1) ^ (cc & 3)) << 3) + ((q & 1) << 2);
      *(ushort4*)&xs[e] = wv;
    }
    __syncthreads();

    for (int tap = 0; tap < 9; ++tap) {
      const int ky = tap / 3, kx = tap - ky * 3;
      bf16x8 a[9];
      const unsigned short* wp = wt + (((size_t)(cb * 9 + tap) * 9) << 9) + (lane << 3);
#pragma unroll
      for (int m = 0; m < 9; ++m) a[m] = *(const bf16x8*)(wp + (m << 9));
#pragma unroll
      for (int n = 0; n < 2; ++n) {
        int px = ((wave << 1) + n) * 16 + ln;
        int row = (px >> 6) + ky, cc = (px & 63) + kx;
        int e = ((row * 66 + cc) << 5) + ((kg ^ (cc & 3)) << 3);
        bf16x8 bv = *(const bf16x8*)&xs[e];
#pragma unroll
        for (int m = 0; m < 9; ++m)
          acc[m][n] = __builtin_amdgcn_mfma_f32_16x16x32_bf16(a[m], bv, acc[m][n], 0, 0, 0);
      }
    }
  }

#pragma unroll
  for (int n = 0; n < 2; ++n) {
    int px = ((wave << 1) + n) * 16 + ln;
    int y = y0 + (px >> 6), x = px & 63;
#pragma unroll
    for (int m = 0; m < 9; ++m) {
      int cob = m * 16 + (kg << 2);
#pragma unroll
      for (int r = 0; r < 4; ++r)
        out[(((size_t)(b * C_OFF + cob + r)) << 12) + (y << 6) + x] =
            acc[m][n][r] + bias[cob + r];
    }
  }
}

// ---------------------------------------------------------------------------
// Kernel 3: deformable conv via MFMA, gather-direct-to-register B-fragments.
// Round-3 skeleton with ONE change: A-fragments load global->register from
// L2-resident wd (0.79 MB) per K-step in two 8-tile halves — no LDS staging,
// no barriers in the K-loop (only the 2 geo barriers per group). Waves
// free-run, hiding the 32 scalar gather loads per K-step.
// ---------------------------------------------------------------------------
__global__ __launch_bounds__(256, 3) void dcn_mfma(
    const float* __restrict__ fu, const float* __restrict__ off,
    const unsigned short* __restrict__ wt, const float* __restrict__ bias,
    float* __restrict__ out) {
  const int b = blockIdx.x >> 6, h = blockIdx.x & 63;
  const int tid = threadIdx.x;
  const int wave = tid >> 6, lane = tid & 63;
  const int kg = lane >> 4, ln = lane & 15;
  const int px = (wave << 4) + ln;   // this wave's pixel (n index)

  __shared__ __align__(16) uint4 geo[576];  // [tap*64+px], 9.2KB (only LDS)

  f32x4 acc[16];
#pragma unroll
  for (int m = 0; m < 16; ++m) acc[m] = {0.f, 0.f, 0.f, 0.f};

  for (int g = 0; g < OFFG; ++g) {
    __syncthreads();  // protect geo from previous group's readers
    // ---- geometry per (tap, px): packed corner indices + fp16 weights
    for (int idx = tid; idx < 576; idx += 256) {
      int tap = idx >> 6, p = idx & 63;
      int ky = tap / 3, kx = tap - ky * 3;
      int ch = (g * 9 + tap) * 2;
      float oy = off[(((size_t)(b * C_OFF + ch)) << 12) + (h << 6) + p];
      float ox = off[(((size_t)(b * C_OFF + ch + 1)) << 12) + (h << 6) + p];
      float py = (float)(h - 1 + ky) + oy;
      float pxs = (float)(p - 1 + kx) + ox;
      float y0f = floorf(py), x0f = floorf(pxs);
      int y0 = (int)y0f, x0 = (int)x0f;
      float fy = py - y0f, fx = pxs - x0f;
      float vy0 = (y0 >= 0 && y0 < 64) ? 1.f : 0.f;
      float vy1 = (y0 + 1 >= 0 && y0 + 1 < 64) ? 1.f : 0.f;
      float vx0 = (x0 >= 0 && x0 < 64) ? 1.f : 0.f;
      float vx1 = (x0 + 1 >= 0 && x0 + 1 < 64) ? 1.f : 0.f;
      int yc0 = min(max(y0, 0), 63), xc0 = min(max(x0, 0), 63);
      int yc1 = min(max(y0 + 1, 0), 63), xc1 = min(max(x0 + 1, 0), 63);
      uint4 gg;
      gg.x = (unsigned)((yc0 << 6) + xc0) | ((unsigned)((yc0 << 6) + xc1) << 16);
      gg.y = (unsigned)((yc1 << 6) + xc0) | ((unsigned)((yc1 << 6) + xc1) << 16);
      gg.z = packh2((1.f - fy) * (1.f - fx) * vy0 * vx0,
                    (1.f - fy) * fx * vy0 * vx1);
      gg.w = packh2(fy * (1.f - fx) * vy1 * vx0, fy * fx * vy1 * vx1);
      geo[idx] = gg;
    }
    __syncthreads();

    const float* gbase = fu + (((size_t)(b * C_IN + g * CG)) << 12);
    for (int ks = 0; ks < 6; ++ks) {
      const int t = g * 6 + ks;
      // ---- build B fragment in registers: 8 bilinear samples at this px
      bf16x8 bv;
#pragma unroll
      for (int i = 0; i < 8; ++i) {
        int r = ks * 32 + (kg << 3) + i;
        int ci = r / 9;
        int tap = r - ci * 9;
        ci = ci < CG ? ci : CG - 1;  // pad rows: A is zero there, keep in-bounds
        uint4 gg = geo[(tap << 6) + px];
        const float* pl = gbase + ((size_t)ci << 12);
        float v00 = pl[gg.x & 0xFFFFu];
        float v01 = pl[gg.x >> 16];
        float v10 = pl[gg.y & 0xFFFFu];
        float v11 = pl[gg.y >> 16];
        float s = h2f_lo(gg.z) * v00 + h2f_hi(gg.z) * v01 +
                  h2f_lo(gg.w) * v10 + h2f_hi(gg.w) * v11;
        bv[i] = (short)f2bf(s);
      }

      // ---- A: 16 coalesced 16B register loads from L2 + 16 MFMAs, 2 halves
      const unsigned short* wp = wt + (size_t)t * 8192 + lane * 8;
#pragma unroll
      for (int half = 0; half < 2; ++half) {
        bf16x8 a[8];
#pragma unroll
        for (int j = 0; j < 8; ++j)
          a[j] = *(const bf16x8*)(wp + (half * 8 + j) * 512);
#pragma unroll
        for (int j = 0; j < 8; ++j)
          acc[half * 8 + j] =
              __builtin_amdgcn_mfma_f32_16x16x32_bf16(a[j], bv, acc[half * 8 + j], 0, 0, 0);
      }
    }
  }

  // ---- epilogue: bias + SiLU.  C/D: col(px)=lane&15, row=kg*4+r
#pragma unroll
  for (int mt = 0; mt < 16; ++mt) {
    int cob = mt * 16 + (kg << 2);
#pragma unroll
    for (int r = 0; r < 4; ++r) {
      float y = acc[mt][r] + bias[cob + r];
      out[(((size_t)(b * C_OUT + cob + r)) << 12) + (h << 6) + px] =
          y / (1.f + expf(-y));
    }
  }
}

// ---------------------------------------------------------------------------
extern "C" void kernel_launch(void* const* d_in, const int* in_sizes, int n_in,
                              void* d_out, int out_size, void* d_ws, size_t ws_size,
                              hipStream_t stream) {
  const float* feat_arm = (const float*)d_in[0];
  const float* feat_up  = (const float*)d_in[1];
  const float* off_w    = (const float*)d_in[2];
  const float* off_b    = (const float*)d_in[3];
  const float* dcn_w    = (const float*)d_in[4];
  const float* dcn_b    = (const float*)d_in[5];
  float* out = (float*)d_out;

  float* ws = (float*)d_ws;
  float* offbuf = ws;                                        // OFF_ELEMS f32
  unsigned short* wo = (unsigned short*)(ws + OFF_ELEMS);    // WOFF_PACK bf16
  unsigned short* wd = wo + WOFF_PACK;                       // WDCN_PACK bf16

  pack_w<<<(WDCN_PACK + 255) / 256, 256, 0, stream>>>(off_w, dcn_w, wo, wd);
  offs_conv_mfma<<<BN * 32, 256, 0, stream>>>(feat_arm, feat_up, wo, off_b, offbuf);
  dcn_mfma<<<BN * 64, 256, 0, stream>>>(feat_up, offbuf, wd, dcn_b, out);
}

// Round 6
// 379.719 us; speedup vs baseline: 1.1969x; 1.1969x over previous
//
#include <hip/hip_runtime.h>
#include <math.h>

// feat_arm/feat_up: [16,144,64,64] f32
// off_w: [144,288,3,3], off_b: [144]
// dcn_w: [256,144,3,3], dcn_b: [256]
// out: [16,256,64,64] f32 (silu)
constexpr int BN = 16;
constexpr int C_IN = 144, C_CAT = 288, C_OFF = 144, C_OUT = 256;
constexpr int OFFG = 8, CG = 18;

constexpr int OFF_ELEMS = BN * C_OFF * 64 * 64;   // fp32 offsets in ws
constexpr int WOFF_PACK = 9 * 9 * 9 * 512;        // 373248 bf16 (cb,tap,mtile,lane,i)
constexpr int WDCN_PACK = 8 * 6 * 16 * 512;       // 393216 bf16 (t=g*6+ks, mtile, lane, i)

typedef __attribute__((ext_vector_type(8))) short bf16x8;
typedef __attribute__((ext_vector_type(4))) float f32x4;

__device__ __forceinline__ unsigned short f2bf(float f) {
  unsigned u = __builtin_bit_cast(unsigned, f);
  return (unsigned short)((u + 0x7FFFu + ((u >> 16) & 1u)) >> 16);  // RNE, finite inputs
}

__device__ __forceinline__ unsigned packh2(float a, float b) {
  unsigned short ha = __builtin_bit_cast(unsigned short, (_Float16)a);
  unsigned short hb = __builtin_bit_cast(unsigned short, (_Float16)b);
  return (unsigned)ha | ((unsigned)hb << 16);
}
__device__ __forceinline__ float h2f_lo(unsigned u) {
  return (float)__builtin_bit_cast(_Float16, (unsigned short)(u & 0xFFFFu));
}
__device__ __forceinline__ float h2f_hi(unsigned u) {
  return (float)__builtin_bit_cast(_Float16, (unsigned short)(u >> 16));
}

// async global->LDS, 16B per lane, wave-uniform LDS base
__device__ __forceinline__ void gload_lds16(const void* g, void* l) {
  __builtin_amdgcn_global_load_lds(
      (const __attribute__((address_space(1))) unsigned*)g,
      (__attribute__((address_space(3))) unsigned*)l, 16, 0, 0);
}

// ---------------------------------------------------------------------------
// Kernel 1: pack both weight tensors into MFMA A-fragment order (bf16).
// A-frag slot (lane, i) of a 16x32 tile: m = lane&15, k = (lane>>4)*8 + i.
// (round-3 proven version)
// ---------------------------------------------------------------------------
__global__ __launch_bounds__(256) void pack_w(
    const float* __restrict__ off_w, const float* __restrict__ dcn_w,
    unsigned short* __restrict__ wo, unsigned short* __restrict__ wd) {
  int idx = blockIdx.x * 256 + threadIdx.x;
  if (idx < WOFF_PACK) {
    int i = idx & 7, lane = (idx >> 3) & 63, t = idx >> 9;
    int mt = t % 9; t /= 9;
    int tap = t % 9, cb = t / 9;
    int co = mt * 16 + (lane & 15);
    int ci = cb * 32 + ((lane >> 4) << 3) + i;
    wo[idx] = f2bf(off_w[(co * C_CAT + ci) * 9 + tap]);
  }
  if (idx < WDCN_PACK) {
    int i = idx & 7, lane = (idx >> 3) & 63, t = idx >> 9;
    int mt = t & 15; t >>= 4;
    int ks = t % 6, g = t / 6;
    int co = mt * 16 + (lane & 15);
    int r = ks * 32 + ((lane >> 4) << 3) + i;
    float v = 0.f;
    if (r < 162) {
      int ci = r / 9, tap = r - ci * 9;
      v = dcn_w[(co * C_IN + g * CG + ci) * 9 + tap];
    }
    wd[idx] = f2bf(v);
  }
}

// ---------------------------------------------------------------------------
// Kernel 2: offset conv via MFMA (9 shifted GEMMs). Identical to round 3.
// ---------------------------------------------------------------------------
__global__ __launch_bounds__(256) void offs_conv_mfma(
    const float* __restrict__ fa, const float* __restrict__ fu,
    const unsigned short* __restrict__ wt, const float* __restrict__ bias,
    float* __restrict__ out) {
  const int b = blockIdx.x >> 5;
  const int y0 = (blockIdx.x & 31) << 1;
  const int tid = threadIdx.x;
  const int wave = tid >> 6, lane = tid & 63;
  const int kg = lane >> 4, ln = lane & 15;

  __shared__ __align__(16) unsigned short xs[4 * 66 * 32];

  f32x4 acc[9][2];
#pragma unroll
  for (int m = 0; m < 9; ++m)
#pragma unroll
    for (int n = 0; n < 2; ++n) acc[m][n] = {0.f, 0.f, 0.f, 0.f};

  for (int cb = 0; cb < 9; ++cb) {
    __syncthreads();
    for (int idx = tid; idx < 2112; idx += 256) {
      int q = idx / 264;
      int rem = idx - q * 264;
      int row = rem / 66;
      int cc = rem - row * 66;
      int y = y0 - 1 + row, x = cc - 1;
      ushort4 wv = make_ushort4(0, 0, 0, 0);
      if (y >= 0 && y < 64 && x >= 0 && x < 64) {
        int cib = cb * 32 + (q << 2);
        const float* p = (cib < C_IN)
                             ? fa + (((size_t)(b * C_IN + cib)) << 12)
                             : fu + (((size_t)(b * C_IN + cib - C_IN)) << 12);
        int o = (y << 6) + x;
        wv.x = f2bf(p[o]);
        wv.y = f2bf(p[o + 4096]);
        wv.z = f2bf(p[o + 8192]);
        wv.w = f2bf(p[o + 12288]);
      }
      int e = ((row * 66 + cc) << 5) + (((q >> 1) ^ (cc & 3)) << 3) + ((q & 1) << 2);
      *(ushort4*)&xs[e] = wv;
    }
    __syncthreads();

    for (int tap = 0; tap < 9; ++tap) {
      const int ky = tap / 3, kx = tap - ky * 3;
      bf16x8 a[9];
      const unsigned short* wp = wt + (((size_t)(cb * 9 + tap) * 9) << 9) + (lane << 3);
#pragma unroll
      for (int m = 0; m < 9; ++m) a[m] = *(const bf16x8*)(wp + (m << 9));
#pragma unroll
      for (int n = 0; n < 2; ++n) {
        int px = ((wave << 1) + n) * 16 + ln;
        int row = (px >> 6) + ky, cc = (px & 63) + kx;
        int e = ((row * 66 + cc) << 5) + ((kg ^ (cc & 3)) << 3);
        bf16x8 bv = *(const bf16x8*)&xs[e];
#pragma unroll
        for (int m = 0; m < 9; ++m)
          acc[m][n] = __builtin_amdgcn_mfma_f32_16x16x32_bf16(a[m], bv, acc[m][n], 0, 0, 0);
      }
    }
  }

#pragma unroll
  for (int n = 0; n < 2; ++n) {
    int px = ((wave << 1) + n) * 16 + ln;
    int y = y0 + (px >> 6), x = px & 63;
#pragma unroll
    for (int m = 0; m < 9; ++m) {
      int cob = m * 16 + (kg << 2);
#pragma unroll
      for (int r = 0; r < 4; ++r)
        out[(((size_t)(b * C_OFF + cob + r)) << 12) + (y << 6) + x] =
            acc[m][n][r] + bias[cob + r];
    }
  }
}

// ---------------------------------------------------------------------------
// Kernel 3: deformable conv via MFMA. Round-3 skeleton (LDS-staged dbuf A)
// with the gather restructured px-fastest through a cols LDS tile:
//   gather: wave-uniform (ci,tap), lanes = 64 consecutive px -> each corner
//           load touches ~4-6 cache lines (was ~20-30) -> 5x less L1 pressure
//   cols[r][66] bf16: writes stride-1 (conflict-free); B-frag reads r-stride
//           33 dwords -> kg*8+i maps banks bijectively (conflict-free)
//   rows 162..191 zeroed once (K padded to 192 for 6 MFMA K-steps)
// ---------------------------------------------------------------------------
__global__ __launch_bounds__(256, 2) void dcn_mfma(
    const float* __restrict__ fu, const float* __restrict__ off,
    const unsigned short* __restrict__ wt, const float* __restrict__ bias,
    float* __restrict__ out) {
  const int b = blockIdx.x >> 6, h = blockIdx.x & 63;
  const int tid = threadIdx.x;
  const int wave = tid >> 6, lane = tid & 63;
  const int kg = lane >> 4, ln = lane & 15;
  const int px = (wave << 4) + ln;   // this wave's pixel (n index)

  __shared__ __align__(16) uint4 geo[576];               // [tap*64+px], 9.2KB
  __shared__ __align__(16) unsigned short cols[192 * 66];// [r][px pad 66], 25.3KB
  __shared__ __align__(16) unsigned short wl[2][8192];   // A dbuf, 2x16KB

  f32x4 acc[16];
#pragma unroll
  for (int m = 0; m < 16; ++m) acc[m] = {0.f, 0.f, 0.f, 0.f};

  // zero K-pad rows 162..191 once (30*66 ushort = 990 dwords, dword-aligned)
  for (int i = tid; i < 990; i += 256)
    ((unsigned*)(cols + 162 * 66))[i] = 0u;

  // prologue: stage A chunk t=0 into buffer 0
  {
    const unsigned short* src = wt + (wave * 4) * 512 + lane * 8;
#pragma unroll
    for (int j = 0; j < 4; ++j)
      gload_lds16(src + j * 512, &wl[0][(wave * 4 + j) * 512]);
  }

  int t = 0;
  for (int g = 0; g < OFFG; ++g) {
    __syncthreads();  // prev group's cols readers + geo readers done
    // ---- phase 1: geometry per (tap, px): corner indices + fp16 weights
    for (int idx = tid; idx < 576; idx += 256) {
      int tap = idx >> 6, p = idx & 63;
      int ky = tap / 3, kx = tap - ky * 3;
      int ch = (g * 9 + tap) * 2;
      float oy = off[(((size_t)(b * C_OFF + ch)) << 12) + (h << 6) + p];
      float ox = off[(((size_t)(b * C_OFF + ch + 1)) << 12) + (h << 6) + p];
      float py = (float)(h - 1 + ky) + oy;
      float pxs = (float)(p - 1 + kx) + ox;
      float y0f = floorf(py), x0f = floorf(pxs);
      int y0 = (int)y0f, x0 = (int)x0f;
      float fy = py - y0f, fx = pxs - x0f;
      float vy0 = (y0 >= 0 && y0 < 64) ? 1.f : 0.f;
      float vy1 = (y0 + 1 >= 0 && y0 + 1 < 64) ? 1.f : 0.f;
      float vx0 = (x0 >= 0 && x0 < 64) ? 1.f : 0.f;
      float vx1 = (x0 + 1 >= 0 && x0 + 1 < 64) ? 1.f : 0.f;
      int yc0 = min(max(y0, 0), 63), xc0 = min(max(x0, 0), 63);
      int yc1 = min(max(y0 + 1, 0), 63), xc1 = min(max(x0 + 1, 0), 63);
      uint4 gg;
      gg.x = (unsigned)((yc0 << 6) + xc0) | ((unsigned)((yc0 << 6) + xc1) << 16);
      gg.y = (unsigned)((yc1 << 6) + xc0) | ((unsigned)((yc1 << 6) + xc1) << 16);
      gg.z = packh2((1.f - fy) * (1.f - fx) * vy0 * vx0,
                    (1.f - fy) * fx * vy0 * vx1);
      gg.w = packh2(fy * (1.f - fx) * vy1 * vx0, fy * fx * vy1 * vx1);
      geo[idx] = gg;
    }
    __syncthreads();

    // ---- phase 2: gather -> cols[r][px], px-fastest (coalesced corners)
    const float* gbase = fu + (((size_t)(b * C_IN + g * CG)) << 12);
    for (int idx = tid; idx < 162 * 64; idx += 256) {
      int rr = idx >> 6;              // wave-uniform (r = ci*9 + tap)
      int p = idx & 63;               // lane = px -> coalesced
      int ci = rr / 9;
      int tap = rr - ci * 9;
      uint4 gg = geo[(tap << 6) + p];
      const float* pl = gbase + ((size_t)ci << 12);
      float v00 = pl[gg.x & 0xFFFFu];
      float v01 = pl[gg.x >> 16];
      float v10 = pl[gg.y & 0xFFFFu];
      float v11 = pl[gg.y >> 16];
      float s = h2f_lo(gg.z) * v00 + h2f_hi(gg.z) * v01 +
                h2f_lo(gg.w) * v10 + h2f_hi(gg.w) * v11;
      cols[rr * 66 + p] = f2bf(s);
    }
    __syncthreads();

    // ---- phase 3: 6 MFMA K-steps over this group's 192 (padded) k
    for (int ks = 0; ks < 6; ++ks, ++t) {
      // B fragment: 8 scalar LDS reads (conflict-free via 66-pad)
      bf16x8 bv;
      const unsigned short* cp = &cols[(ks * 32 + (kg << 3)) * 66 + px];
#pragma unroll
      for (int i = 0; i < 8; ++i) bv[i] = (short)cp[i * 66];

      __syncthreads();  // stage(t) drained (vmcnt0); prev buf readers done

      // issue stage(t+1) into the other buffer
      if (t < 47) {
        const unsigned short* src =
            wt + (size_t)(t + 1) * 8192 + (wave * 4) * 512 + lane * 8;
        unsigned short* dst = wl[(t + 1) & 1];
#pragma unroll
        for (int j = 0; j < 4; ++j)
          gload_lds16(src + j * 512, dst + (wave * 4 + j) * 512);
      }

      // 16 MFMAs: all M-tiles against this wave's B fragment
      const unsigned short* wbuf = wl[t & 1] + lane * 8;
#pragma unroll
      for (int mt = 0; mt < 16; ++mt) {
        bf16x8 av = *(const bf16x8*)(wbuf + mt * 512);
        acc[mt] = __builtin_amdgcn_mfma_f32_16x16x32_bf16(av, bv, acc[mt], 0, 0, 0);
      }
    }
  }

  // ---- epilogue: bias + SiLU.  C/D: col(px)=lane&15, row=kg*4+r
#pragma unroll
  for (int mt = 0; mt < 16; ++mt) {
    int cob = mt * 16 + (kg << 2);
#pragma unroll
    for (int r = 0; r < 4; ++r) {
      float y = acc[mt][r] + bias[cob + r];
      out[(((size_t)(b * C_OUT + cob + r)) << 12) + (h << 6) + px] =
          y / (1.f + expf(-y));
    }
  }
}

// ---------------------------------------------------------------------------
extern "C" void kernel_launch(void* const* d_in, const int* in_sizes, int n_in,
                              void* d_out, int out_size, void* d_ws, size_t ws_size,
                              hipStream_t stream) {
  const float* feat_arm = (const float*)d_in[0];
  const float* feat_up  = (const float*)d_in[1];
  const float* off_w    = (const float*)d_in[2];
  const float* off_b    = (const float*)d_in[3];
  const float* dcn_w    = (const float*)d_in[4];
  const float* dcn_b    = (const float*)d_in[5];
  float* out = (float*)d_out;

  float* ws = (float*)d_ws;
  float* offbuf = ws;                                        // OFF_ELEMS f32
  unsigned short* wo = (unsigned short*)(ws + OFF_ELEMS);    // WOFF_PACK bf16
  unsigned short* wd = wo + WOFF_PACK;                       // WDCN_PACK bf16

  pack_w<<<(WDCN_PACK + 255) / 256, 256, 0, stream>>>(off_w, dcn_w, wo, wd);
  offs_conv_mfma<<<BN * 32, 256, 0, stream>>>(feat_arm, feat_up, wo, off_b, offbuf);
  dcn_mfma<<<BN * 64, 256, 0, stream>>>(feat_up, offbuf, wd, dcn_b, out);
}

// Round 7
// 377.004 us; speedup vs baseline: 1.2056x; 1.0072x over previous
//
#include <hip/hip_runtime.h>
#include <math.h>

// feat_arm/feat_up: [16,144,64,64] f32
// off_w: [144,288,3,3], off_b: [144]
// dcn_w: [256,144,3,3], dcn_b: [256]
// out: [16,256,64,64] f32 (silu)
constexpr int BN = 16;
constexpr int C_IN = 144, C_CAT = 288, C_OFF = 144, C_OUT = 256;
constexpr int OFFG = 8, CG = 18;

constexpr int OFF_ELEMS = BN * C_OFF * 64 * 64;   // fp32 offsets in ws
constexpr int WOFF_PACK = 9 * 9 * 9 * 512;        // 373248 bf16 (cb,tap,mtile,lane,i)
constexpr int WDCN_PACK = 8 * 6 * 16 * 512;       // 393216 bf16 (t=g*6+ks, mtile, lane, i)

typedef __attribute__((ext_vector_type(8))) short bf16x8;
typedef __attribute__((ext_vector_type(4))) float f32x4;

__device__ __forceinline__ unsigned short f2bf(float f) {
  unsigned u = __builtin_bit_cast(unsigned, f);
  return (unsigned short)((u + 0x7FFFu + ((u >> 16) & 1u)) >> 16);  // RNE, finite inputs
}

__device__ __forceinline__ unsigned packh2(float a, float b) {
  unsigned short ha = __builtin_bit_cast(unsigned short, (_Float16)a);
  unsigned short hb = __builtin_bit_cast(unsigned short, (_Float16)b);
  return (unsigned)ha | ((unsigned)hb << 16);
}
__device__ __forceinline__ float h2f_lo(unsigned u) {
  return (float)__builtin_bit_cast(_Float16, (unsigned short)(u & 0xFFFFu));
}
__device__ __forceinline__ float h2f_hi(unsigned u) {
  return (float)__builtin_bit_cast(_Float16, (unsigned short)(u >> 16));
}

// async global->LDS, 16B per lane, wave-uniform LDS base
__device__ __forceinline__ void gload_lds16(const void* g, void* l) {
  __builtin_amdgcn_global_load_lds(
      (const __attribute__((address_space(1))) unsigned*)g,
      (__attribute__((address_space(3))) unsigned*)l, 16, 0, 0);
}

// ---------------------------------------------------------------------------
// Kernel 1: pack both weight tensors into MFMA A-fragment order (bf16).
// A-frag slot (lane, i) of a 16x32 tile: m = lane&15, k = (lane>>4)*8 + i.
// (round-3 proven version)
// ---------------------------------------------------------------------------
__global__ __launch_bounds__(256) void pack_w(
    const float* __restrict__ off_w, const float* __restrict__ dcn_w,
    unsigned short* __restrict__ wo, unsigned short* __restrict__ wd) {
  int idx = blockIdx.x * 256 + threadIdx.x;
  if (idx < WOFF_PACK) {
    int i = idx & 7, lane = (idx >> 3) & 63, t = idx >> 9;
    int mt = t % 9; t /= 9;
    int tap = t % 9, cb = t / 9;
    int co = mt * 16 + (lane & 15);
    int ci = cb * 32 + ((lane >> 4) << 3) + i;
    wo[idx] = f2bf(off_w[(co * C_CAT + ci) * 9 + tap]);
  }
  if (idx < WDCN_PACK) {
    int i = idx & 7, lane = (idx >> 3) & 63, t = idx >> 9;
    int mt = t & 15; t >>= 4;
    int ks = t % 6, g = t / 6;
    int co = mt * 16 + (lane & 15);
    int r = ks * 32 + ((lane >> 4) << 3) + i;
    float v = 0.f;
    if (r < 162) {
      int ci = r / 9, tap = r - ci * 9;
      v = dcn_w[(co * C_IN + g * CG + ci) * 9 + tap];
    }
    wd[idx] = f2bf(v);
  }
}

// ---------------------------------------------------------------------------
// Kernel 2: offset conv via MFMA (9 shifted GEMMs). Identical to round 3.
// ---------------------------------------------------------------------------
__global__ __launch_bounds__(256) void offs_conv_mfma(
    const float* __restrict__ fa, const float* __restrict__ fu,
    const unsigned short* __restrict__ wt, const float* __restrict__ bias,
    float* __restrict__ out) {
  const int b = blockIdx.x >> 5;
  const int y0 = (blockIdx.x & 31) << 1;
  const int tid = threadIdx.x;
  const int wave = tid >> 6, lane = tid & 63;
  const int kg = lane >> 4, ln = lane & 15;

  __shared__ __align__(16) unsigned short xs[4 * 66 * 32];

  f32x4 acc[9][2];
#pragma unroll
  for (int m = 0; m < 9; ++m)
#pragma unroll
    for (int n = 0; n < 2; ++n) acc[m][n] = {0.f, 0.f, 0.f, 0.f};

  for (int cb = 0; cb < 9; ++cb) {
    __syncthreads();
    for (int idx = tid; idx < 2112; idx += 256) {
      int q = idx / 264;
      int rem = idx - q * 264;
      int row = rem / 66;
      int cc = rem - row * 66;
      int y = y0 - 1 + row, x = cc - 1;
      ushort4 wv = make_ushort4(0, 0, 0, 0);
      if (y >= 0 && y < 64 && x >= 0 && x < 64) {
        int cib = cb * 32 + (q << 2);
        const float* p = (cib < C_IN)
                             ? fa + (((size_t)(b * C_IN + cib)) << 12)
                             : fu + (((size_t)(b * C_IN + cib - C_IN)) << 12);
        int o = (y << 6) + x;
        wv.x = f2bf(p[o]);
        wv.y = f2bf(p[o + 4096]);
        wv.z = f2bf(p[o + 8192]);
        wv.w = f2bf(p[o + 12288]);
      }
      int e = ((row * 66 + cc) << 5) + (((q >> 1) ^ (cc & 3)) << 3) + ((q & 1) << 2);
      *(ushort4*)&xs[e] = wv;
    }
    __syncthreads();

    for (int tap = 0; tap < 9; ++tap) {
      const int ky = tap / 3, kx = tap - ky * 3;
      bf16x8 a[9];
      const unsigned short* wp = wt + (((size_t)(cb * 9 + tap) * 9) << 9) + (lane << 3);
#pragma unroll
      for (int m = 0; m < 9; ++m) a[m] = *(const bf16x8*)(wp + (m << 9));
#pragma unroll
      for (int n = 0; n < 2; ++n) {
        int px = ((wave << 1) + n) * 16 + ln;
        int row = (px >> 6) + ky, cc = (px & 63) + kx;
        int e = ((row * 66 + cc) << 5) + ((kg ^ (cc & 3)) << 3);
        bf16x8 bv = *(const bf16x8*)&xs[e];
#pragma unroll
        for (int m = 0; m < 9; ++m)
          acc[m][n] = __builtin_amdgcn_mfma_f32_16x16x32_bf16(a[m], bv, acc[m][n], 0, 0, 0);
      }
    }
  }

#pragma unroll
  for (int n = 0; n < 2; ++n) {
    int px = ((wave << 1) + n) * 16 + ln;
    int y = y0 + (px >> 6), x = px & 63;
#pragma unroll
    for (int m = 0; m < 9; ++m) {
      int cob = m * 16 + (kg << 2);
#pragma unroll
      for (int r = 0; r < 4; ++r)
        out[(((size_t)(b * C_OFF + cob + r)) << 12) + (y << 6) + x] =
            acc[m][n][r] + bias[cob + r];
    }
  }
}

// ---------------------------------------------------------------------------
// Kernel 3: deformable conv via MFMA. Round-6 skeleton, 512 threads (8 waves,
// 2M x 4N split): same 67.5KB LDS -> still 2 blocks/CU but 16 waves/CU =
// 4 waves/SIMD (2x latency cover). Gather loop is 24 clean iterations
// (K-pad rows folded in, written 0) with unroll 4 -> 16 loads in flight.
// ---------------------------------------------------------------------------
__global__ __launch_bounds__(512, 4) void dcn_mfma(
    const float* __restrict__ fu, const float* __restrict__ off,
    const unsigned short* __restrict__ wt, const float* __restrict__ bias,
    float* __restrict__ out) {
  const int b = blockIdx.x >> 6, h = blockIdx.x & 63;
  const int tid = threadIdx.x;
  const int wave = tid >> 6, lane = tid & 63;
  const int kg = lane >> 4, ln = lane & 15;
  const int wm = wave >> 2, wn = wave & 3;   // M-half, N-tile
  const int px = (wn << 4) + ln;             // this wave's pixel (n index)

  __shared__ __align__(16) uint4 geo[576];               // [tap*64+px], 9.2KB
  __shared__ __align__(16) unsigned short cols[192 * 66];// [r][px pad 66], 25.3KB
  __shared__ __align__(16) unsigned short wl[2][8192];   // A dbuf, 2x16KB

  f32x4 acc[8];
#pragma unroll
  for (int m = 0; m < 8; ++m) acc[m] = {0.f, 0.f, 0.f, 0.f};

  // prologue: stage A chunk t=0 into buffer 0 (16 rows of 1KB, 2 per wave)
  {
    const unsigned short* src = wt + (wave * 2) * 512 + lane * 8;
#pragma unroll
    for (int j = 0; j < 2; ++j)
      gload_lds16(src + j * 512, &wl[0][(wave * 2 + j) * 512]);
  }

  int t = 0;
  for (int g = 0; g < OFFG; ++g) {
    __syncthreads();  // prev group's cols/geo readers done
    // ---- phase 1: geometry per (tap, px): corner indices + fp16 weights
    for (int idx = tid; idx < 576; idx += 512) {
      int tap = idx >> 6, p = idx & 63;
      int ky = tap / 3, kx = tap - ky * 3;
      int ch = (g * 9 + tap) * 2;
      float oy = off[(((size_t)(b * C_OFF + ch)) << 12) + (h << 6) + p];
      float ox = off[(((size_t)(b * C_OFF + ch + 1)) << 12) + (h << 6) + p];
      float py = (float)(h - 1 + ky) + oy;
      float pxs = (float)(p - 1 + kx) + ox;
      float y0f = floorf(py), x0f = floorf(pxs);
      int y0 = (int)y0f, x0 = (int)x0f;
      float fy = py - y0f, fx = pxs - x0f;
      float vy0 = (y0 >= 0 && y0 < 64) ? 1.f : 0.f;
      float vy1 = (y0 + 1 >= 0 && y0 + 1 < 64) ? 1.f : 0.f;
      float vx0 = (x0 >= 0 && x0 < 64) ? 1.f : 0.f;
      float vx1 = (x0 + 1 >= 0 && x0 + 1 < 64) ? 1.f : 0.f;
      int yc0 = min(max(y0, 0), 63), xc0 = min(max(x0, 0), 63);
      int yc1 = min(max(y0 + 1, 0), 63), xc1 = min(max(x0 + 1, 0), 63);
      uint4 gg;
      gg.x = (unsigned)((yc0 << 6) + xc0) | ((unsigned)((yc0 << 6) + xc1) << 16);
      gg.y = (unsigned)((yc1 << 6) + xc0) | ((unsigned)((yc1 << 6) + xc1) << 16);
      gg.z = packh2((1.f - fy) * (1.f - fx) * vy0 * vx0,
                    (1.f - fy) * fx * vy0 * vx1);
      gg.w = packh2(fy * (1.f - fx) * vy1 * vx0, fy * fx * vy1 * vx1);
      geo[idx] = gg;
    }
    __syncthreads();

    // ---- phase 2: gather -> cols[r][px], px-fastest (coalesced corners).
    // 192*64 items = 24 clean iterations @512 thr; rows >=162 write 0 (K pad).
    const float* gbase = fu + (((size_t)(b * C_IN + g * CG)) << 12);
#pragma unroll 4
    for (int it = 0; it < 24; ++it) {
      int idx = it * 512 + tid;
      int rr = idx >> 6;              // wave-uniform (r = ci*9 + tap)
      int p = idx & 63;               // lane = px -> coalesced
      unsigned short val = 0;
      if (rr < 162) {                 // wave-uniform branch
        int ci = rr / 9;
        int tap = rr - ci * 9;
        uint4 gg = geo[(tap << 6) + p];
        const float* pl = gbase + ((size_t)ci << 12);
        float v00 = pl[gg.x & 0xFFFFu];
        float v01 = pl[gg.x >> 16];
        float v10 = pl[gg.y & 0xFFFFu];
        float v11 = pl[gg.y >> 16];
        float s = h2f_lo(gg.z) * v00 + h2f_hi(gg.z) * v01 +
                  h2f_lo(gg.w) * v10 + h2f_hi(gg.w) * v11;
        val = f2bf(s);
      }
      cols[rr * 66 + p] = val;
    }
    __syncthreads();

    // ---- phase 3: 6 MFMA K-steps over this group's 192 (padded) k
    for (int ks = 0; ks < 6; ++ks, ++t) {
      // B fragment: 8 scalar LDS reads (conflict-free via 66-pad)
      bf16x8 bv;
      const unsigned short* cp = &cols[(ks * 32 + (kg << 3)) * 66 + px];
#pragma unroll
      for (int i = 0; i < 8; ++i) bv[i] = (short)cp[i * 66];

      __syncthreads();  // stage(t) drained (vmcnt0); prev buf readers done

      // issue stage(t+1) into the other buffer (2 rows per wave)
      if (t < 47) {
        const unsigned short* src =
            wt + (size_t)(t + 1) * 8192 + (wave * 2) * 512 + lane * 8;
        unsigned short* dst = wl[(t + 1) & 1];
#pragma unroll
        for (int j = 0; j < 2; ++j)
          gload_lds16(src + j * 512, dst + (wave * 2 + j) * 512);
      }

      // 8 MFMAs: this wave's M-half against its B fragment
      const unsigned short* wbuf = wl[t & 1] + (wm * 8) * 512 + lane * 8;
#pragma unroll
      for (int j = 0; j < 8; ++j) {
        bf16x8 av = *(const bf16x8*)(wbuf + j * 512);
        acc[j] = __builtin_amdgcn_mfma_f32_16x16x32_bf16(av, bv, acc[j], 0, 0, 0);
      }
    }
  }

  // ---- epilogue: bias + SiLU.  C/D: col(px)=lane&15, row=kg*4+r
#pragma unroll
  for (int j = 0; j < 8; ++j) {
    int cob = (wm * 8 + j) * 16 + (kg << 2);
#pragma unroll
    for (int r = 0; r < 4; ++r) {
      float y = acc[j][r] + bias[cob + r];
      out[(((size_t)(b * C_OUT + cob + r)) << 12) + (h << 6) + px] =
          y / (1.f + expf(-y));
    }
  }
}

// ---------------------------------------------------------------------------
extern "C" void kernel_launch(void* const* d_in, const int* in_sizes, int n_in,
                              void* d_out, int out_size, void* d_ws, size_t ws_size,
                              hipStream_t stream) {
  const float* feat_arm = (const float*)d_in[0];
  const float* feat_up  = (const float*)d_in[1];
  const float* off_w    = (const float*)d_in[2];
  const float* off_b    = (const float*)d_in[3];
  const float* dcn_w    = (const float*)d_in[4];
  const float* dcn_b    = (const float*)d_in[5];
  float* out = (float*)d_out;

  float* ws = (float*)d_ws;
  float* offbuf = ws;                                        // OFF_ELEMS f32
  unsigned short* wo = (unsigned short*)(ws + OFF_ELEMS);    // WOFF_PACK bf16
  unsigned short* wd = wo + WOFF_PACK;                       // WDCN_PACK bf16

  pack_w<<<(WDCN_PACK + 255) / 256, 256, 0, stream>>>(off_w, dcn_w, wo, wd);
  offs_conv_mfma<<<BN * 32, 256, 0, stream>>>(feat_arm, feat_up, wo, off_b, offbuf);
  dcn_mfma<<<BN * 64, 512, 0, stream>>>(feat_up, offbuf, wd, dcn_b, out);
}